// Round 17
// baseline (197.292 us; speedup 1.0000x reference)
//
#include <hip/hip_runtime.h>
#include <hip/hip_bf16.h>

#define EMB 64
#define HID 256

typedef __attribute__((ext_vector_type(8))) short short8_t;   // 8 bf16 = 4 VGPRs
typedef __attribute__((ext_vector_type(4))) float f32x4;

// fp32 -> bf16 bits, round-to-nearest-even (matches HW conversion)
__device__ __forceinline__ unsigned short f2bf(float f)
{
    union { float f; unsigned int u; } c; c.f = f;
    unsigned int u = c.u;
    u += 0x7fffu + ((u >> 16) & 1u);
    return (unsigned short)(u >> 16);
}
__device__ __forceinline__ float bf2f(unsigned short b)
{
    union { unsigned int u; float f; } c; c.u = ((unsigned int)b) << 16;
    return c.f;
}

// ---------------------------------------------------------------------------
// prep: fused {zero counts | emb->bf16 | W0/W1/W2 -> MFMA fragment-major bf16}
// Wf[((nt*KC + kc)*64 + lane)*8 + j] = W[kc*32 + kg*8 + j][nt*16 + lr]
// ---------------------------------------------------------------------------
__global__ __launch_bounds__(256) void prep_kernel(
    const float* __restrict__ emb, const float* __restrict__ W0,
    const float* __restrict__ W1, const float* __restrict__ W2,
    int* __restrict__ counts, unsigned short* __restrict__ embb,
    unsigned short* __restrict__ W0f, unsigned short* __restrict__ W1f,
    unsigned short* __restrict__ W2f, int M, int zb, int cb)
{
    int b = blockIdx.x;
    if (b < zb) {                              // zero counts[M]
        int idx = (b * 256 + threadIdx.x) * 4;
        if (idx + 3 < M) {
            int4 z; z.x = 0; z.y = 0; z.z = 0; z.w = 0;
            *(int4*)&counts[idx] = z;
        } else {
            for (int i = idx; i < M; ++i) counts[i] = 0;
        }
        return;
    }
    b -= zb;
    if (b < cb) {                              // emb fp32 -> bf16
        int idx = (b * 256 + threadIdx.x) * 4;
        if (idx + 3 < M * EMB) {
            float4 v = *(const float4*)&emb[idx];
            ushort4 o;
            o.x = f2bf(v.x); o.y = f2bf(v.y); o.z = f2bf(v.z); o.w = f2bf(v.w);
            *(ushort4*)&embb[idx] = o;
        }
        return;
    }
    b -= cb;
    if (b < 8) {                               // W0f: 16 nt x 2 kc x 64 lanes
        int i    = b * 256 + threadIdx.x;
        int lane = i & 63;
        int kc   = (i >> 6) & 1;
        int nt   = i >> 7;
        int lr   = lane & 15, kg = lane >> 4;
        unsigned short tmp[8];
#pragma unroll
        for (int j = 0; j < 8; ++j)
            tmp[j] = f2bf(W0[(kc * 32 + kg * 8 + j) * HID + nt * 16 + lr]);
        *(short8_t*)&W0f[(size_t)i * 8] = *(short8_t*)tmp;
        return;
    }
    b -= 8;
    if (b < 32) {                              // W1f: 16 nt x 8 kc x 64 lanes
        int i    = b * 256 + threadIdx.x;
        int lane = i & 63;
        int kc   = (i >> 6) & 7;
        int nt   = i >> 9;
        int lr   = lane & 15, kg = lane >> 4;
        unsigned short tmp[8];
#pragma unroll
        for (int j = 0; j < 8; ++j)
            tmp[j] = f2bf(W1[(kc * 32 + kg * 8 + j) * HID + nt * 16 + lr]);
        *(short8_t*)&W1f[(size_t)i * 8] = *(short8_t*)tmp;
        return;
    }
    b -= 32;
    {                                          // W2f
        int i    = b * 256 + threadIdx.x;
        int lane = i & 63;
        int kc   = (i >> 6) & 7;
        int nt   = i >> 9;
        int lr   = lane & 15, kg = lane >> 4;
        unsigned short tmp[8];
#pragma unroll
        for (int j = 0; j < 8; ++j)
            tmp[j] = f2bf(W2[(kc * 32 + kg * 8 + j) * HID + nt * 16 + lr]);
        *(short8_t*)&W2f[(size_t)i * 8] = *(short8_t*)tmp;
    }
}

// ---------------------------------------------------------------------------
// CSR build: histogram -> exclusive scan (2 kernels) -> bucket scatter
// ---------------------------------------------------------------------------
__global__ __launch_bounds__(256) void hist_kernel(
    const int* __restrict__ row, int* __restrict__ counts, int E)
{
    int base = (blockIdx.x * 256 + threadIdx.x) * 4;
    if (base + 3 < E) {
        int4 r4 = *(const int4*)&row[base];
        atomicAdd(&counts[r4.x], 1);
        atomicAdd(&counts[r4.y], 1);
        atomicAdd(&counts[r4.z], 1);
        atomicAdd(&counts[r4.w], 1);
    } else {
        for (int i = base; i < E; ++i) atomicAdd(&counts[row[i]], 1);
    }
}

__global__ __launch_bounds__(256) void scan_phase1(
    const int* __restrict__ counts, int* __restrict__ excl,
    int* __restrict__ blockSums, int n)
{
    __shared__ int s[256];
    int t = threadIdx.x;
    int base = blockIdx.x * 1024 + t * 4;
    int4 v = {0, 0, 0, 0};
    if (base + 3 < n) {
        v = *(const int4*)&counts[base];
    } else {
        if (base + 0 < n) v.x = counts[base + 0];
        if (base + 1 < n) v.y = counts[base + 1];
        if (base + 2 < n) v.z = counts[base + 2];
        if (base + 3 < n) v.w = counts[base + 3];
    }
    int tsum = v.x + v.y + v.z + v.w;
    s[t] = tsum;
    __syncthreads();
#pragma unroll
    for (int off = 1; off < 256; off <<= 1) {
        int val = (t >= off) ? s[t - off] : 0;
        __syncthreads();
        s[t] += val;
        __syncthreads();
    }
    if (t == 255) blockSums[blockIdx.x] = s[255];
    int e0 = s[t] - tsum;
    int e1 = e0 + v.x;
    int e2 = e1 + v.y;
    int e3 = e2 + v.z;
    if (base + 0 < n) excl[base + 0] = e0;
    if (base + 1 < n) excl[base + 1] = e1;
    if (base + 2 < n) excl[base + 2] = e2;
    if (base + 3 < n) excl[base + 3] = e3;
}

// fused phase2+3: every block redundantly exclusive-scans blockSums (nb<=256)
// in LDS, then applies its chunk's offset and inits the cursor.
__global__ __launch_bounds__(256) void scan_phase23(
    int* __restrict__ offsets, const int* __restrict__ blockSums,
    int* __restrict__ cursor, int n, int nb)
{
    __shared__ int s[256];
    __shared__ int ex[256];
    int t = threadIdx.x;
    int v = (t < nb) ? blockSums[t] : 0;
    s[t] = v;
    __syncthreads();
#pragma unroll
    for (int off = 1; off < 256; off <<= 1) {
        int val = (t >= off) ? s[t - off] : 0;
        __syncthreads();
        s[t] += val;
        __syncthreads();
    }
    ex[t] = s[t] - v;      // exclusive prefix of blockSums
    __syncthreads();
    int i = blockIdx.x * 256 + t;
    if (i < n) {
        int o = offsets[i] + ex[i >> 10];
        offsets[i] = o;
        cursor[i]  = o;
    }
}

// bucket scatter: 1 edge per thread
__global__ __launch_bounds__(256) void scatter_kernel(
    const int* __restrict__ row, const int* __restrict__ col,
    const float* __restrict__ val, int* __restrict__ cursor,
    uint2* __restrict__ edata, int E)
{
    int e = blockIdx.x * 256 + threadIdx.x;
    if (e >= E) return;
    int r = row[e];
    int pos = atomicAdd(&cursor[r], 1);
    uint2 d;
    d.x = (unsigned)col[e];
    d.y = __float_as_uint(val[e]);
    edata[pos] = d;
}

// ---------------------------------------------------------------------------
// pull SpMM v4: lane-group edge parallelism (R16 config)
// ---------------------------------------------------------------------------
#define ROWS_PER_WAVE 8
__global__ __launch_bounds__(256) void pull_kernel(
    const int* __restrict__ offsets, const int* __restrict__ counts,
    const uint2* __restrict__ edata, const unsigned short* __restrict__ embb,
    unsigned short* __restrict__ xb, int Nn)
{
    const int nw   = gridDim.x * 4;
    const int wid  = blockIdx.x * 4 + (threadIdx.x >> 6);
    const int lane = threadIdx.x & 63;
    const int g    = lane >> 4;          // edge-group 0..3
    const int sl   = lane & 15;          // sub-lane: dims sl*4 .. sl*4+3
    if (wid >= Nn) return;

    int beg = __builtin_amdgcn_readfirstlane(offsets[wid]);
    int cnt = __builtin_amdgcn_readfirstlane(counts[wid]);
    for (int r = wid; r < Nn; r += nw) {
        int rn = r + nw;
        int begN = 0, cntN = 0;
        if (rn < Nn) {
            begN = __builtin_amdgcn_readfirstlane(offsets[rn]);
            cntN = __builtin_amdgcn_readfirstlane(counts[rn]);
        }

        f32x4 acc = {0.f, 0.f, 0.f, 0.f};
        for (int i = 0; i < cnt; i += 8) {
            int i0 = i + g;       bool c0 = (i0 < cnt); i0 = c0 ? i0 : 0;
            int i1 = i + 4 + g;   bool c1 = (i1 < cnt); i1 = c1 ? i1 : 0;
            uint2 ed0 = edata[beg + i0];
            uint2 ed1 = edata[beg + i1];
            uint2 g0 = *(const uint2*)&embb[(size_t)ed0.x * EMB + sl * 4];
            uint2 g1 = *(const uint2*)&embb[(size_t)ed1.x * EMB + sl * 4];
            float v0 = c0 ? __uint_as_float(ed0.y) : 0.f;
            float v1 = c1 ? __uint_as_float(ed1.y) : 0.f;
            acc.x += v0 * bf2f((unsigned short)(g0.x & 0xffffu));
            acc.y += v0 * bf2f((unsigned short)(g0.x >> 16));
            acc.z += v0 * bf2f((unsigned short)(g0.y & 0xffffu));
            acc.w += v0 * bf2f((unsigned short)(g0.y >> 16));
            acc.x += v1 * bf2f((unsigned short)(g1.x & 0xffffu));
            acc.y += v1 * bf2f((unsigned short)(g1.x >> 16));
            acc.z += v1 * bf2f((unsigned short)(g1.y & 0xffffu));
            acc.w += v1 * bf2f((unsigned short)(g1.y >> 16));
        }
        // butterfly reduce across the 4 groups (lanes ^16, ^32)
        acc.x += __shfl_xor(acc.x, 16, 64);
        acc.y += __shfl_xor(acc.y, 16, 64);
        acc.z += __shfl_xor(acc.z, 16, 64);
        acc.w += __shfl_xor(acc.w, 16, 64);
        acc.x += __shfl_xor(acc.x, 32, 64);
        acc.y += __shfl_xor(acc.y, 32, 64);
        acc.z += __shfl_xor(acc.z, 32, 64);
        acc.w += __shfl_xor(acc.w, 32, 64);
        if (g == 0) {
            uint2 o;
            o.x = (unsigned)f2bf(acc.x) | ((unsigned)f2bf(acc.y) << 16);
            o.y = (unsigned)f2bf(acc.z) | ((unsigned)f2bf(acc.w) << 16);
            *(uint2*)&xb[(size_t)r * EMB + sl * 4] = o;
        }
        beg = begN; cnt = cntN;
    }
}

// ---------------------------------------------------------------------------
// fused 3-layer MLP, BM=64 with 8 waves (512 thr): wave (h,q) = (w>>2, w&3)
// handles row-half h (rows h*32..h*32+31, 2 m-tiles) and col-quarter q.
// Two waves share each weight fragment (L1/L2 hit) -> half the per-row
// weight L2 traffic of BM=32. Cross-barrier W prefetch as in R15.
// LDS: H = 64x256 bf16 (32KB, swizzled), reused as 8 x 4KB fp32 staging.
// ---------------------------------------------------------------------------
__global__ __launch_bounds__(512) void mlp_fused(
    const unsigned short* __restrict__ xb,   // [M][64]  bf16
    const unsigned short* __restrict__ W0f,  // frag-major, KC=2
    const unsigned short* __restrict__ W1f,  // frag-major, KC=8
    const unsigned short* __restrict__ W2f,  // frag-major, KC=8
    float* __restrict__ out, int M)
{
    __shared__ unsigned short H[64 * 256];   // 32 KB

    const int t    = threadIdx.x;
    const int lane = t & 63;
    const int w    = t >> 6;                 // wave 0..7
    const int h    = w >> 2;                 // row-half 0..1
    const int q    = w & 3;                  // col-quarter 0..3
    const int lr   = lane & 15;
    const int kg   = lane >> 4;
    const int row0 = blockIdx.x * 64;
    char* Hb = (char*)H;

#define HOFF(row, bytecol) ((((row) * 512) + (bytecol)) ^ (((row) & 7) << 4))

    // ---------------- phase 1: h0 = relu(x @ W0), K = 64 ----------------
    short8_t ax[2][2];
#pragma unroll
    for (int kc = 0; kc < 2; ++kc)
#pragma unroll
        for (int m = 0; m < 2; ++m) {
            int gr = row0 + h * 32 + m * 16 + lr;
            ax[kc][m] = *(const short8_t*)(xb + (size_t)(gr < M ? gr : 0) * EMB
                                           + kc * 32 + kg * 8);
        }
    f32x4 acc[2][4] = {};
#pragma unroll
    for (int kc = 0; kc < 2; ++kc) {
        short8_t b[4];
#pragma unroll
        for (int n = 0; n < 4; ++n)
            b[n] = *(const short8_t*)&W0f[(size_t)(((q * 4 + n) * 2 + kc) * 64 + lane) * 8];
#pragma unroll
        for (int m = 0; m < 2; ++m)
#pragma unroll
            for (int n = 0; n < 4; ++n)
                acc[m][n] = __builtin_amdgcn_mfma_f32_16x16x32_bf16(
                    ax[kc][m], b[n], acc[m][n], 0, 0, 0);
    }

    // prefetch W1 kc=0,1 into registers BEFORE the barrier
    short8_t pb[2][4];
#pragma unroll
    for (int n = 0; n < 4; ++n) {
        pb[0][n] = *(const short8_t*)&W1f[(size_t)(((q * 4 + n) * 8 + 0) * 64 + lane) * 8];
        pb[1][n] = *(const short8_t*)&W1f[(size_t)(((q * 4 + n) * 8 + 1) * 64 + lane) * 8];
    }

#pragma unroll
    for (int m = 0; m < 2; ++m)
#pragma unroll
        for (int r = 0; r < 4; ++r)
#pragma unroll
            for (int n = 0; n < 4; ++n)
                *(unsigned short*)(Hb + HOFF(h * 32 + m * 16 + kg * 4 + r,
                                             (q * 64 + n * 16 + lr) * 2)) =
                    f2bf(fmaxf(acc[m][n][r], 0.f));
    __syncthreads();

    // ---------------- phase 2: h1 = relu(h0 @ W1), K = 256 ----------------
    f32x4 acc2[2][4] = {};
#pragma unroll
    for (int kc = 0; kc < 8; ++kc) {
        short8_t b[4];
#pragma unroll
        for (int n = 0; n < 4; ++n) b[n] = pb[kc & 1][n];
        // rolling depth-2 prefetch; kc=6,7 fetch W2 kc=0,1 across the barriers
#pragma unroll
        for (int n = 0; n < 4; ++n) {
            if (kc < 6)
                pb[kc & 1][n] = *(const short8_t*)
                    &W1f[(size_t)(((q * 4 + n) * 8 + kc + 2) * 64 + lane) * 8];
            else
                pb[kc & 1][n] = *(const short8_t*)
                    &W2f[(size_t)(((q * 4 + n) * 8 + (kc - 6)) * 64 + lane) * 8];
        }
        short8_t a[2];
#pragma unroll
        for (int m = 0; m < 2; ++m)
            a[m] = *(const short8_t*)(Hb + HOFF(h * 32 + m * 16 + lr,
                                                kc * 64 + kg * 16));
#pragma unroll
        for (int m = 0; m < 2; ++m)
#pragma unroll
            for (int n = 0; n < 4; ++n)
                acc2[m][n] = __builtin_amdgcn_mfma_f32_16x16x32_bf16(
                    a[m], b[n], acc2[m][n], 0, 0, 0);
    }
    __syncthreads();   // all h0 reads done
#pragma unroll
    for (int m = 0; m < 2; ++m)
#pragma unroll
        for (int r = 0; r < 4; ++r)
#pragma unroll
            for (int n = 0; n < 4; ++n)
                *(unsigned short*)(Hb + HOFF(h * 32 + m * 16 + kg * 4 + r,
                                             (q * 64 + n * 16 + lr) * 2)) =
                    f2bf(fmaxf(acc2[m][n][r], 0.f));
    __syncthreads();   // h1 visible; pb holds W2 kc=0,1

    // ---------------- phase 3: out = h1 @ W2, K = 256 ----------------
    f32x4 acc3[2][4] = {};
#pragma unroll
    for (int kc = 0; kc < 8; ++kc) {
        short8_t b[4];
#pragma unroll
        for (int n = 0; n < 4; ++n) b[n] = pb[kc & 1][n];
#pragma unroll
        for (int n = 0; n < 4; ++n) {
            if (kc < 6)
                pb[kc & 1][n] = *(const short8_t*)
                    &W2f[(size_t)(((q * 4 + n) * 8 + kc + 2) * 64 + lane) * 8];
        }
        short8_t a[2];
#pragma unroll
        for (int m = 0; m < 2; ++m)
            a[m] = *(const short8_t*)(Hb + HOFF(h * 32 + m * 16 + lr,
                                                kc * 64 + kg * 16));
#pragma unroll
        for (int m = 0; m < 2; ++m)
#pragma unroll
            for (int n = 0; n < 4; ++n)
                acc3[m][n] = __builtin_amdgcn_mfma_f32_16x16x32_bf16(
                    a[m], b[n], acc3[m][n], 0, 0, 0);
    }
    __syncthreads();   // phase-3 H reads complete; H free for staging

    // ------------- epilogue: LDS-bounce -> coalesced dwordx4 stores -------------
    float* Hf = (float*)H;            // per-wave private 4KB region: w*1024 floats
#pragma unroll
    for (int m = 0; m < 2; ++m) {
#pragma unroll
        for (int n = 0; n < 4; ++n)
#pragma unroll
            for (int r = 0; r < 4; ++r)
                Hf[w * 1024 + (kg * 4 + r) * 64 + n * 16 + lr] = acc3[m][n][r];
#pragma unroll
        for (int p = 0; p < 4; ++p) {
            int rl = (lane >> 4) + p * 4;                   // 0..15
            f32x4 v = *(const f32x4*)&Hf[w * 1024 + rl * 64 + (lane & 15) * 4];
            int gr = row0 + h * 32 + m * 16 + rl;
            if (gr < M)
                *(f32x4*)&out[(size_t)gr * HID + q * 64 + (lane & 15) * 4] = v;
        }
        __syncthreads();   // staging region reused across m iterations
    }
#undef HOFF
}

// ---------------------------------------------------------------------------
// fallback path kernels (ws too small): atomic scatter SpMM + fp32 GEMM
// ---------------------------------------------------------------------------
__global__ __launch_bounds__(256) void spmm_kernel(
    const int* __restrict__ row, const int* __restrict__ col,
    const float* __restrict__ val, const float* __restrict__ emb,
    float* __restrict__ x, int E)
{
    int gid  = blockIdx.x * blockDim.x + threadIdx.x;
    int e    = gid >> 6;
    int lane = gid & 63;
    if (e >= E) return;
    unsafeAtomicAdd(&x[(size_t)row[e] * EMB + lane],
                    val[e] * emb[(size_t)col[e] * EMB + lane]);
}

template<int K, bool RELU>
__global__ __launch_bounds__(256) void gemm_f32(
    const float* A, const float* __restrict__ B, float* C, int M)
{
    __shared__ float As[64][17];
    __shared__ float Bs[16][256];

    const int t    = threadIdx.x;
    const int tn   = t & 15;
    const int row0 = blockIdx.x * 64;
    const int sk = t & 15;
    const int sm = (t >> 4) * 4;

    float acc[4][16];
#pragma unroll
    for (int i = 0; i < 4; ++i)
#pragma unroll
        for (int j = 0; j < 16; ++j) acc[i][j] = 0.f;

    const int mB = ((t & 63) >> 4) * 4;
    const int wq = t >> 6;
    const int myM = (wq * 16) + mB;

    for (int k0 = 0; k0 < K; k0 += 16) {
        __syncthreads();
#pragma unroll
        for (int i = 0; i < 4; ++i) {
            int m  = sm + i;
            int gr = row0 + m;
            As[m][sk] = (gr < M) ? A[(size_t)gr * K + k0 + sk] : 0.f;
        }
#pragma unroll
        for (int r = 0; r < 16; ++r)
            Bs[r][t] = B[(size_t)(k0 + r) * 256 + t];
        __syncthreads();

#pragma unroll
        for (int kk = 0; kk < 16; ++kk) {
            float a0 = As[myM + 0][kk];
            float a1 = As[myM + 1][kk];
            float a2 = As[myM + 2][kk];
            float a3 = As[myM + 3][kk];
            float4 b[4];
#pragma unroll
            for (int j = 0; j < 4; ++j)
                b[j] = *(const float4*)&Bs[kk][tn * 4 + j * 64];
#pragma unroll
            for (int j = 0; j < 4; ++j) {
                acc[0][j*4+0] += a0 * b[j].x;  acc[0][j*4+1] += a0 * b[j].y;
                acc[0][j*4+2] += a0 * b[j].z;  acc[0][j*4+3] += a0 * b[j].w;
                acc[1][j*4+0] += a1 * b[j].x;  acc[1][j*4+1] += a1 * b[j].y;
                acc[1][j*4+2] += a1 * b[j].z;  acc[1][j*4+3] += a1 * b[j].w;
                acc[2][j*4+0] += a2 * b[j].x;  acc[2][j*4+1] += a2 * b[j].y;
                acc[2][j*4+2] += a2 * b[j].z;  acc[2][j*4+3] += a2 * b[j].w;
                acc[3][j*4+0] += a3 * b[j].x;  acc[3][j*4+1] += a3 * b[j].y;
                acc[3][j*4+2] += a3 * b[j].z;  acc[3][j*4+3] += a3 * b[j].w;
            }
        }
    }

#pragma unroll
    for (int i = 0; i < 4; ++i) {
        int gr = row0 + myM + i;
        if (gr < M) {
#pragma unroll
            for (int j = 0; j < 4; ++j) {
                float4 o;
                o.x = acc[i][j*4+0]; o.y = acc[i][j*4+1];
                o.z = acc[i][j*4+2]; o.w = acc[i][j*4+3];
                if (RELU) {
                    o.x = fmaxf(o.x, 0.f); o.y = fmaxf(o.y, 0.f);
                    o.z = fmaxf(o.z, 0.f); o.w = fmaxf(o.w, 0.f);
                }
                *(float4*)&C[(size_t)gr * 256 + tn * 4 + j * 64] = o;
            }
        }
    }
}

extern "C" void kernel_launch(void* const* d_in, const int* in_sizes, int n_in,
                              void* d_out, int out_size, void* d_ws, size_t ws_size,
                              hipStream_t stream)
{
    const int*   row = (const int*)d_in[0];
    const int*   col = (const int*)d_in[1];
    const float* val = (const float*)d_in[2];
    const float* emb = (const float*)d_in[3];
    const float* W0  = (const float*)d_in[4];
    const float* W1  = (const float*)d_in[5];
    const float* W2  = (const float*)d_in[6];
    float* out = (float*)d_out;

    const int E = in_sizes[0];
    const int M = in_sizes[3] / EMB;   // num nodes

    char* ws = (char*)d_ws;

    // ---- ws layout (256B-aligned regions) ----
    size_t off = 0;
    auto alloc = [&](size_t bytes) { size_t o = off; off = (off + bytes + 255) & ~(size_t)255; return o; };
    const size_t off_counts = alloc((size_t)M * 4);
    const size_t off_offs   = alloc((size_t)M * 4);
    const size_t off_cursor = alloc((size_t)M * 4);
    const size_t off_bsums  = alloc(1024);
    const size_t off_edata  = alloc((size_t)E * 8);
    const size_t off_embb   = alloc((size_t)M * EMB * 2);
    const size_t off_xb     = alloc((size_t)M * EMB * 2);
    const size_t off_w0     = alloc((size_t)EMB * HID * 2);
    const size_t off_w1     = alloc((size_t)HID * HID * 2);
    const size_t off_w2     = alloc((size_t)HID * HID * 2);
    const size_t need       = off;

    if (ws_size >= need) {
        int*   counts = (int*)(ws + off_counts);
        int*   offs   = (int*)(ws + off_offs);
        int*   cursor = (int*)(ws + off_cursor);
        int*   bsums  = (int*)(ws + off_bsums);
        uint2* edata  = (uint2*)(ws + off_edata);
        unsigned short* embb = (unsigned short*)(ws + off_embb);
        unsigned short* xb  = (unsigned short*)(ws + off_xb);
        unsigned short* W0f = (unsigned short*)(ws + off_w0);
        unsigned short* W1f = (unsigned short*)(ws + off_w1);
        unsigned short* W2f = (unsigned short*)(ws + off_w2);

        // fused prep: zero counts + emb->bf16 + weight fragment-major pack
        int zb = (M / 4 + 255) / 256;
        int cb = ((M * EMB) / 4 + 255) / 256;
        int prep_blocks = zb + cb + 8 + 32 + 32;
        prep_kernel<<<prep_blocks, 256, 0, stream>>>(
            emb, W0, W1, W2, counts, embb, W0f, W1f, W2f, M, zb, cb);

        // CSR build
        hist_kernel<<<(E / 4 + 255) / 256, 256, 0, stream>>>(row, counts, E);
        int nb = (M + 1023) / 1024;
        scan_phase1<<<nb, 256, 0, stream>>>(counts, offs, bsums, M);
        scan_phase23<<<(M + 255) / 256, 256, 0, stream>>>(offs, bsums, cursor, M, nb);
        scatter_kernel<<<(E + 255) / 256, 256, 0, stream>>>(row, col, val, cursor, edata, E);

        // pull SpMM -> xb (bf16): grid-stride, lane-group edge parallelism
        int pull_blocks = (M + 4 * ROWS_PER_WAVE - 1) / (4 * ROWS_PER_WAVE);
        pull_kernel<<<pull_blocks, 256, 0, stream>>>(offs, counts, edata, embb, xb, M);

        // fused 3-layer MLP -> out (BM=64, 8 waves, cross-barrier W prefetch)
        int gblocks = (M + 63) / 64;
        mlp_fused<<<gblocks, 512, 0, stream>>>(xb, W0f, W1f, W2f, out, M);
    } else {
        // fp32 fallback (ws too small): atomic scatter SpMM + fp32 GEMMs
        float* x = (float*)ws;
        (void)hipMemsetAsync(x, 0, (size_t)M * EMB * sizeof(float), stream);
        spmm_kernel<<<(E + 3) / 4, 256, 0, stream>>>(row, col, val, emb, x, E);
        int gblocks = (M + 63) / 64;
        gemm_f32<EMB, true ><<<gblocks, 256, 0, stream>>>(x,   W0, out, M);
        gemm_f32<HID, true ><<<gblocks, 256, 0, stream>>>(out, W1, out, M);
        gemm_f32<HID, false><<<gblocks, 256, 0, stream>>>(out, W2, out, M);
    }
}

// Round 18
// 175.740 us; speedup vs baseline: 1.1226x; 1.1226x over previous
//
#include <hip/hip_runtime.h>
#include <hip/hip_bf16.h>

#define EMB 64
#define HID 256

typedef __attribute__((ext_vector_type(8))) short short8_t;   // 8 bf16 = 4 VGPRs
typedef __attribute__((ext_vector_type(4))) float f32x4;

// fp32 -> bf16 bits, round-to-nearest-even (matches HW conversion)
__device__ __forceinline__ unsigned short f2bf(float f)
{
    union { float f; unsigned int u; } c; c.f = f;
    unsigned int u = c.u;
    u += 0x7fffu + ((u >> 16) & 1u);
    return (unsigned short)(u >> 16);
}
__device__ __forceinline__ float bf2f(unsigned short b)
{
    union { unsigned int u; float f; } c; c.u = ((unsigned int)b) << 16;
    return c.f;
}

// ---------------------------------------------------------------------------
// prep: fused {zero counts | emb->bf16 | W0/W1/W2 -> MFMA fragment-major bf16}
// Wf[((nt*KC + kc)*64 + lane)*8 + j] = W[kc*32 + kg*8 + j][nt*16 + lr]
// ---------------------------------------------------------------------------
__global__ __launch_bounds__(256) void prep_kernel(
    const float* __restrict__ emb, const float* __restrict__ W0,
    const float* __restrict__ W1, const float* __restrict__ W2,
    int* __restrict__ counts, unsigned short* __restrict__ embb,
    unsigned short* __restrict__ W0f, unsigned short* __restrict__ W1f,
    unsigned short* __restrict__ W2f, int M, int zb, int cb)
{
    int b = blockIdx.x;
    if (b < zb) {                              // zero counts[M]
        int idx = (b * 256 + threadIdx.x) * 4;
        if (idx + 3 < M) {
            int4 z; z.x = 0; z.y = 0; z.z = 0; z.w = 0;
            *(int4*)&counts[idx] = z;
        } else {
            for (int i = idx; i < M; ++i) counts[i] = 0;
        }
        return;
    }
    b -= zb;
    if (b < cb) {                              // emb fp32 -> bf16
        int idx = (b * 256 + threadIdx.x) * 4;
        if (idx + 3 < M * EMB) {
            float4 v = *(const float4*)&emb[idx];
            ushort4 o;
            o.x = f2bf(v.x); o.y = f2bf(v.y); o.z = f2bf(v.z); o.w = f2bf(v.w);
            *(ushort4*)&embb[idx] = o;
        }
        return;
    }
    b -= cb;
    if (b < 8) {                               // W0f: 16 nt x 2 kc x 64 lanes
        int i    = b * 256 + threadIdx.x;
        int lane = i & 63;
        int kc   = (i >> 6) & 1;
        int nt   = i >> 7;
        int lr   = lane & 15, kg = lane >> 4;
        unsigned short tmp[8];
#pragma unroll
        for (int j = 0; j < 8; ++j)
            tmp[j] = f2bf(W0[(kc * 32 + kg * 8 + j) * HID + nt * 16 + lr]);
        *(short8_t*)&W0f[(size_t)i * 8] = *(short8_t*)tmp;
        return;
    }
    b -= 8;
    if (b < 32) {                              // W1f: 16 nt x 8 kc x 64 lanes
        int i    = b * 256 + threadIdx.x;
        int lane = i & 63;
        int kc   = (i >> 6) & 7;
        int nt   = i >> 9;
        int lr   = lane & 15, kg = lane >> 4;
        unsigned short tmp[8];
#pragma unroll
        for (int j = 0; j < 8; ++j)
            tmp[j] = f2bf(W1[(kc * 32 + kg * 8 + j) * HID + nt * 16 + lr]);
        *(short8_t*)&W1f[(size_t)i * 8] = *(short8_t*)tmp;
        return;
    }
    b -= 32;
    {                                          // W2f
        int i    = b * 256 + threadIdx.x;
        int lane = i & 63;
        int kc   = (i >> 6) & 7;
        int nt   = i >> 9;
        int lr   = lane & 15, kg = lane >> 4;
        unsigned short tmp[8];
#pragma unroll
        for (int j = 0; j < 8; ++j)
            tmp[j] = f2bf(W2[(kc * 32 + kg * 8 + j) * HID + nt * 16 + lr]);
        *(short8_t*)&W2f[(size_t)i * 8] = *(short8_t*)tmp;
    }
}

// ---------------------------------------------------------------------------
// CSR build: histogram -> exclusive scan (2 kernels) -> bucket scatter
// ---------------------------------------------------------------------------
__global__ __launch_bounds__(256) void hist_kernel(
    const int* __restrict__ row, int* __restrict__ counts, int E)
{
    int base = (blockIdx.x * 256 + threadIdx.x) * 4;
    if (base + 3 < E) {
        int4 r4 = *(const int4*)&row[base];
        atomicAdd(&counts[r4.x], 1);
        atomicAdd(&counts[r4.y], 1);
        atomicAdd(&counts[r4.z], 1);
        atomicAdd(&counts[r4.w], 1);
    } else {
        for (int i = base; i < E; ++i) atomicAdd(&counts[row[i]], 1);
    }
}

__global__ __launch_bounds__(256) void scan_phase1(
    const int* __restrict__ counts, int* __restrict__ excl,
    int* __restrict__ blockSums, int n)
{
    __shared__ int s[256];
    int t = threadIdx.x;
    int base = blockIdx.x * 1024 + t * 4;
    int4 v = {0, 0, 0, 0};
    if (base + 3 < n) {
        v = *(const int4*)&counts[base];
    } else {
        if (base + 0 < n) v.x = counts[base + 0];
        if (base + 1 < n) v.y = counts[base + 1];
        if (base + 2 < n) v.z = counts[base + 2];
        if (base + 3 < n) v.w = counts[base + 3];
    }
    int tsum = v.x + v.y + v.z + v.w;
    s[t] = tsum;
    __syncthreads();
#pragma unroll
    for (int off = 1; off < 256; off <<= 1) {
        int val = (t >= off) ? s[t - off] : 0;
        __syncthreads();
        s[t] += val;
        __syncthreads();
    }
    if (t == 255) blockSums[blockIdx.x] = s[255];
    int e0 = s[t] - tsum;
    int e1 = e0 + v.x;
    int e2 = e1 + v.y;
    int e3 = e2 + v.z;
    if (base + 0 < n) excl[base + 0] = e0;
    if (base + 1 < n) excl[base + 1] = e1;
    if (base + 2 < n) excl[base + 2] = e2;
    if (base + 3 < n) excl[base + 3] = e3;
}

// fused phase2+3: every block redundantly exclusive-scans blockSums (nb<=256)
// in LDS, then applies its chunk's offset and inits the cursor.
__global__ __launch_bounds__(256) void scan_phase23(
    int* __restrict__ offsets, const int* __restrict__ blockSums,
    int* __restrict__ cursor, int n, int nb)
{
    __shared__ int s[256];
    __shared__ int ex[256];
    int t = threadIdx.x;
    int v = (t < nb) ? blockSums[t] : 0;
    s[t] = v;
    __syncthreads();
#pragma unroll
    for (int off = 1; off < 256; off <<= 1) {
        int val = (t >= off) ? s[t - off] : 0;
        __syncthreads();
        s[t] += val;
        __syncthreads();
    }
    ex[t] = s[t] - v;      // exclusive prefix of blockSums
    __syncthreads();
    int i = blockIdx.x * 256 + t;
    if (i < n) {
        int o = offsets[i] + ex[i >> 10];
        offsets[i] = o;
        cursor[i]  = o;
    }
}

// bucket scatter: 1 edge per thread
__global__ __launch_bounds__(256) void scatter_kernel(
    const int* __restrict__ row, const int* __restrict__ col,
    const float* __restrict__ val, int* __restrict__ cursor,
    uint2* __restrict__ edata, int E)
{
    int e = blockIdx.x * 256 + threadIdx.x;
    if (e >= E) return;
    int r = row[e];
    int pos = atomicAdd(&cursor[r], 1);
    uint2 d;
    d.x = (unsigned)col[e];
    d.y = __float_as_uint(val[e]);
    edata[pos] = d;
}

// ---------------------------------------------------------------------------
// pull SpMM v4: lane-group edge parallelism.
// Wave = 1 row; lane-group g (16 lanes) handles edge i+g (and i+4+g), each
// lane gathering 8B (4 bf16 dims) -> 4 rows per gather instruction. Butterfly
// shfl_xor (16,32) reduces across groups; group 0 stores one coalesced row.
// Grid-stride, ~8 rows/wave, next-row (beg,cnt) prefetch in SGPRs.
// ---------------------------------------------------------------------------
#define ROWS_PER_WAVE 8
__global__ __launch_bounds__(256) void pull_kernel(
    const int* __restrict__ offsets, const int* __restrict__ counts,
    const uint2* __restrict__ edata, const unsigned short* __restrict__ embb,
    unsigned short* __restrict__ xb, int Nn)
{
    const int nw   = gridDim.x * 4;
    const int wid  = blockIdx.x * 4 + (threadIdx.x >> 6);
    const int lane = threadIdx.x & 63;
    const int g    = lane >> 4;          // edge-group 0..3
    const int sl   = lane & 15;          // sub-lane: dims sl*4 .. sl*4+3
    if (wid >= Nn) return;

    int beg = __builtin_amdgcn_readfirstlane(offsets[wid]);
    int cnt = __builtin_amdgcn_readfirstlane(counts[wid]);
    for (int r = wid; r < Nn; r += nw) {
        int rn = r + nw;
        int begN = 0, cntN = 0;
        if (rn < Nn) {
            begN = __builtin_amdgcn_readfirstlane(offsets[rn]);
            cntN = __builtin_amdgcn_readfirstlane(counts[rn]);
        }

        f32x4 acc = {0.f, 0.f, 0.f, 0.f};
        for (int i = 0; i < cnt; i += 8) {
            int i0 = i + g;       bool c0 = (i0 < cnt); i0 = c0 ? i0 : 0;
            int i1 = i + 4 + g;   bool c1 = (i1 < cnt); i1 = c1 ? i1 : 0;
            uint2 ed0 = edata[beg + i0];
            uint2 ed1 = edata[beg + i1];
            uint2 g0 = *(const uint2*)&embb[(size_t)ed0.x * EMB + sl * 4];
            uint2 g1 = *(const uint2*)&embb[(size_t)ed1.x * EMB + sl * 4];
            float v0 = c0 ? __uint_as_float(ed0.y) : 0.f;
            float v1 = c1 ? __uint_as_float(ed1.y) : 0.f;
            acc.x += v0 * bf2f((unsigned short)(g0.x & 0xffffu));
            acc.y += v0 * bf2f((unsigned short)(g0.x >> 16));
            acc.z += v0 * bf2f((unsigned short)(g0.y & 0xffffu));
            acc.w += v0 * bf2f((unsigned short)(g0.y >> 16));
            acc.x += v1 * bf2f((unsigned short)(g1.x & 0xffffu));
            acc.y += v1 * bf2f((unsigned short)(g1.x >> 16));
            acc.z += v1 * bf2f((unsigned short)(g1.y & 0xffffu));
            acc.w += v1 * bf2f((unsigned short)(g1.y >> 16));
        }
        // butterfly reduce across the 4 groups (lanes ^16, ^32)
        acc.x += __shfl_xor(acc.x, 16, 64);
        acc.y += __shfl_xor(acc.y, 16, 64);
        acc.z += __shfl_xor(acc.z, 16, 64);
        acc.w += __shfl_xor(acc.w, 16, 64);
        acc.x += __shfl_xor(acc.x, 32, 64);
        acc.y += __shfl_xor(acc.y, 32, 64);
        acc.z += __shfl_xor(acc.z, 32, 64);
        acc.w += __shfl_xor(acc.w, 32, 64);
        if (g == 0) {
            uint2 o;
            o.x = (unsigned)f2bf(acc.x) | ((unsigned)f2bf(acc.y) << 16);
            o.y = (unsigned)f2bf(acc.z) | ((unsigned)f2bf(acc.w) << 16);
            *(uint2*)&xb[(size_t)r * EMB + sl * 4] = o;
        }
        beg = begN; cnt = cntN;
    }
}

// ---------------------------------------------------------------------------
// fused 3-layer MLP, BM=32 + cross-barrier W-fragment prefetch (R15/R16 config)
// ---------------------------------------------------------------------------
__global__ __launch_bounds__(256) void mlp_fused(
    const unsigned short* __restrict__ xb,   // [M][64]  bf16
    const unsigned short* __restrict__ W0f,  // frag-major, KC=2
    const unsigned short* __restrict__ W1f,  // frag-major, KC=8
    const unsigned short* __restrict__ W2f,  // frag-major, KC=8
    float* __restrict__ out, int M)
{
    __shared__ unsigned short H[32 * 256];   // 16 KB

    const int t    = threadIdx.x;
    const int lane = t & 63;
    const int w    = t >> 6;
    const int lr   = lane & 15;
    const int kg   = lane >> 4;
    const int row0 = blockIdx.x * 32;
    char* Hb = (char*)H;

#define HOFF(row, bytecol) ((((row) * 512) + (bytecol)) ^ (((row) & 7) << 4))

    // ---------------- phase 1: h0 = relu(x @ W0), K = 64 ----------------
    short8_t ax[2][2];
#pragma unroll
    for (int kc = 0; kc < 2; ++kc)
#pragma unroll
        for (int m = 0; m < 2; ++m) {
            int gr = row0 + m * 16 + lr;
            ax[kc][m] = *(const short8_t*)(xb + (size_t)(gr < M ? gr : 0) * EMB
                                           + kc * 32 + kg * 8);
        }
    f32x4 acc[2][4] = {};
#pragma unroll
    for (int kc = 0; kc < 2; ++kc) {
        short8_t b[4];
#pragma unroll
        for (int n = 0; n < 4; ++n)
            b[n] = *(const short8_t*)&W0f[(size_t)(((w * 4 + n) * 2 + kc) * 64 + lane) * 8];
#pragma unroll
        for (int m = 0; m < 2; ++m)
#pragma unroll
            for (int n = 0; n < 4; ++n)
                acc[m][n] = __builtin_amdgcn_mfma_f32_16x16x32_bf16(
                    ax[kc][m], b[n], acc[m][n], 0, 0, 0);
    }

    // prefetch W1 kc=0,1 into registers BEFORE the barrier
    short8_t pb[2][4];
#pragma unroll
    for (int n = 0; n < 4; ++n) {
        pb[0][n] = *(const short8_t*)&W1f[(size_t)(((w * 4 + n) * 8 + 0) * 64 + lane) * 8];
        pb[1][n] = *(const short8_t*)&W1f[(size_t)(((w * 4 + n) * 8 + 1) * 64 + lane) * 8];
    }

#pragma unroll
    for (int m = 0; m < 2; ++m)
#pragma unroll
        for (int r = 0; r < 4; ++r)
#pragma unroll
            for (int n = 0; n < 4; ++n)
                *(unsigned short*)(Hb + HOFF(m * 16 + kg * 4 + r,
                                             (w * 64 + n * 16 + lr) * 2)) =
                    f2bf(fmaxf(acc[m][n][r], 0.f));
    __syncthreads();

    // ---------------- phase 2: h1 = relu(h0 @ W1), K = 256 ----------------
    f32x4 acc2[2][4] = {};
#pragma unroll
    for (int kc = 0; kc < 8; ++kc) {
        short8_t b[4];
#pragma unroll
        for (int n = 0; n < 4; ++n) b[n] = pb[kc & 1][n];
        // rolling depth-2 prefetch; kc=6,7 fetch W2 kc=0,1 across the barriers
#pragma unroll
        for (int n = 0; n < 4; ++n) {
            if (kc < 6)
                pb[kc & 1][n] = *(const short8_t*)
                    &W1f[(size_t)(((w * 4 + n) * 8 + kc + 2) * 64 + lane) * 8];
            else
                pb[kc & 1][n] = *(const short8_t*)
                    &W2f[(size_t)(((w * 4 + n) * 8 + (kc - 6)) * 64 + lane) * 8];
        }
        short8_t a[2];
#pragma unroll
        for (int m = 0; m < 2; ++m)
            a[m] = *(const short8_t*)(Hb + HOFF(m * 16 + lr, kc * 64 + kg * 16));
#pragma unroll
        for (int m = 0; m < 2; ++m)
#pragma unroll
            for (int n = 0; n < 4; ++n)
                acc2[m][n] = __builtin_amdgcn_mfma_f32_16x16x32_bf16(
                    a[m], b[n], acc2[m][n], 0, 0, 0);
    }
    __syncthreads();   // all h0 reads done
#pragma unroll
    for (int m = 0; m < 2; ++m)
#pragma unroll
        for (int r = 0; r < 4; ++r)
#pragma unroll
            for (int n = 0; n < 4; ++n)
                *(unsigned short*)(Hb + HOFF(m * 16 + kg * 4 + r,
                                             (w * 64 + n * 16 + lr) * 2)) =
                    f2bf(fmaxf(acc2[m][n][r], 0.f));
    __syncthreads();   // h1 visible; pb holds W2 kc=0,1

    // ---------------- phase 3: out = h1 @ W2, K = 256 ----------------
    f32x4 acc3[2][4] = {};
#pragma unroll
    for (int kc = 0; kc < 8; ++kc) {
        short8_t b[4];
#pragma unroll
        for (int n = 0; n < 4; ++n) b[n] = pb[kc & 1][n];
#pragma unroll
        for (int n = 0; n < 4; ++n) {
            if (kc < 6)
                pb[kc & 1][n] = *(const short8_t*)
                    &W2f[(size_t)(((w * 4 + n) * 8 + kc + 2) * 64 + lane) * 8];
        }
        short8_t a[2];
#pragma unroll
        for (int m = 0; m < 2; ++m)
            a[m] = *(const short8_t*)(Hb + HOFF(m * 16 + lr, kc * 64 + kg * 16));
#pragma unroll
        for (int m = 0; m < 2; ++m)
#pragma unroll
            for (int n = 0; n < 4; ++n)
                acc3[m][n] = __builtin_amdgcn_mfma_f32_16x16x32_bf16(
                    a[m], b[n], acc3[m][n], 0, 0, 0);
    }
    __syncthreads();   // phase-3 H reads complete; H free for staging

    // ------------- epilogue: LDS-bounce -> coalesced dwordx4 stores -------------
    float* Hf = (float*)H;            // per-wave private 4KB region: w*1024 floats
#pragma unroll
    for (int m = 0; m < 2; ++m) {
#pragma unroll
        for (int n = 0; n < 4; ++n)
#pragma unroll
            for (int r = 0; r < 4; ++r)
                Hf[w * 1024 + (kg * 4 + r) * 64 + n * 16 + lr] = acc3[m][n][r];
#pragma unroll
        for (int p = 0; p < 4; ++p) {
            int rl = (lane >> 4) + p * 4;                   // 0..15
            f32x4 v = *(const f32x4*)&Hf[w * 1024 + rl * 64 + (lane & 15) * 4];
            int gr = row0 + m * 16 + rl;
            if (gr < M)
                *(f32x4*)&out[(size_t)gr * HID + w * 64 + (lane & 15) * 4] = v;
        }
    }
#undef HOFF
}

// ---------------------------------------------------------------------------
// fallback path kernels (ws too small): atomic scatter SpMM + fp32 GEMM
// ---------------------------------------------------------------------------
__global__ __launch_bounds__(256) void spmm_kernel(
    const int* __restrict__ row, const int* __restrict__ col,
    const float* __restrict__ val, const float* __restrict__ emb,
    float* __restrict__ x, int E)
{
    int gid  = blockIdx.x * blockDim.x + threadIdx.x;
    int e    = gid >> 6;
    int lane = gid & 63;
    if (e >= E) return;
    unsafeAtomicAdd(&x[(size_t)row[e] * EMB + lane],
                    val[e] * emb[(size_t)col[e] * EMB + lane]);
}

template<int K, bool RELU>
__global__ __launch_bounds__(256) void gemm_f32(
    const float* A, const float* __restrict__ B, float* C, int M)
{
    __shared__ float As[64][17];
    __shared__ float Bs[16][256];

    const int t    = threadIdx.x;
    const int tn   = t & 15;
    const int row0 = blockIdx.x * 64;
    const int sk = t & 15;
    const int sm = (t >> 4) * 4;

    float acc[4][16];
#pragma unroll
    for (int i = 0; i < 4; ++i)
#pragma unroll
        for (int j = 0; j < 16; ++j) acc[i][j] = 0.f;

    const int mB = ((t & 63) >> 4) * 4;
    const int wq = t >> 6;
    const int myM = (wq * 16) + mB;

    for (int k0 = 0; k0 < K; k0 += 16) {
        __syncthreads();
#pragma unroll
        for (int i = 0; i < 4; ++i) {
            int m  = sm + i;
            int gr = row0 + m;
            As[m][sk] = (gr < M) ? A[(size_t)gr * K + k0 + sk] : 0.f;
        }
#pragma unroll
        for (int r = 0; r < 16; ++r)
            Bs[r][t] = B[(size_t)(k0 + r) * 256 + t];
        __syncthreads();

#pragma unroll
        for (int kk = 0; kk < 16; ++kk) {
            float a0 = As[myM + 0][kk];
            float a1 = As[myM + 1][kk];
            float a2 = As[myM + 2][kk];
            float a3 = As[myM + 3][kk];
            float4 b[4];
#pragma unroll
            for (int j = 0; j < 4; ++j)
                b[j] = *(const float4*)&Bs[kk][tn * 4 + j * 64];
#pragma unroll
            for (int j = 0; j < 4; ++j) {
                acc[0][j*4+0] += a0 * b[j].x;  acc[0][j*4+1] += a0 * b[j].y;
                acc[0][j*4+2] += a0 * b[j].z;  acc[0][j*4+3] += a0 * b[j].w;
                acc[1][j*4+0] += a1 * b[j].x;  acc[1][j*4+1] += a1 * b[j].y;
                acc[1][j*4+2] += a1 * b[j].z;  acc[1][j*4+3] += a1 * b[j].w;
                acc[2][j*4+0] += a2 * b[j].x;  acc[2][j*4+1] += a2 * b[j].y;
                acc[2][j*4+2] += a2 * b[j].z;  acc[2][j*4+3] += a2 * b[j].w;
                acc[3][j*4+0] += a3 * b[j].x;  acc[3][j*4+1] += a3 * b[j].y;
                acc[3][j*4+2] += a3 * b[j].z;  acc[3][j*4+3] += a3 * b[j].w;
            }
        }
    }

#pragma unroll
    for (int i = 0; i < 4; ++i) {
        int gr = row0 + myM + i;
        if (gr < M) {
#pragma unroll
            for (int j = 0; j < 4; ++j) {
                float4 o;
                o.x = acc[i][j*4+0]; o.y = acc[i][j*4+1];
                o.z = acc[i][j*4+2]; o.w = acc[i][j*4+3];
                if (RELU) {
                    o.x = fmaxf(o.x, 0.f); o.y = fmaxf(o.y, 0.f);
                    o.z = fmaxf(o.z, 0.f); o.w = fmaxf(o.w, 0.f);
                }
                *(float4*)&C[(size_t)gr * 256 + tn * 4 + j * 64] = o;
            }
        }
    }
}

extern "C" void kernel_launch(void* const* d_in, const int* in_sizes, int n_in,
                              void* d_out, int out_size, void* d_ws, size_t ws_size,
                              hipStream_t stream)
{
    const int*   row = (const int*)d_in[0];
    const int*   col = (const int*)d_in[1];
    const float* val = (const float*)d_in[2];
    const float* emb = (const float*)d_in[3];
    const float* W0  = (const float*)d_in[4];
    const float* W1  = (const float*)d_in[5];
    const float* W2  = (const float*)d_in[6];
    float* out = (float*)d_out;

    const int E = in_sizes[0];
    const int M = in_sizes[3] / EMB;   // num nodes

    char* ws = (char*)d_ws;

    // ---- ws layout (256B-aligned regions) ----
    size_t off = 0;
    auto alloc = [&](size_t bytes) { size_t o = off; off = (off + bytes + 255) & ~(size_t)255; return o; };
    const size_t off_counts = alloc((size_t)M * 4);
    const size_t off_offs   = alloc((size_t)M * 4);
    const size_t off_cursor = alloc((size_t)M * 4);
    const size_t off_bsums  = alloc(1024);
    const size_t off_edata  = alloc((size_t)E * 8);
    const size_t off_embb   = alloc((size_t)M * EMB * 2);
    const size_t off_xb     = alloc((size_t)M * EMB * 2);
    const size_t off_w0     = alloc((size_t)EMB * HID * 2);
    const size_t off_w1     = alloc((size_t)HID * HID * 2);
    const size_t off_w2     = alloc((size_t)HID * HID * 2);
    const size_t need       = off;

    if (ws_size >= need) {
        int*   counts = (int*)(ws + off_counts);
        int*   offs   = (int*)(ws + off_offs);
        int*   cursor = (int*)(ws + off_cursor);
        int*   bsums  = (int*)(ws + off_bsums);
        uint2* edata  = (uint2*)(ws + off_edata);
        unsigned short* embb = (unsigned short*)(ws + off_embb);
        unsigned short* xb  = (unsigned short*)(ws + off_xb);
        unsigned short* W0f = (unsigned short*)(ws + off_w0);
        unsigned short* W1f = (unsigned short*)(ws + off_w1);
        unsigned short* W2f = (unsigned short*)(ws + off_w2);

        // fused prep: zero counts + emb->bf16 + weight fragment-major pack
        int zb = (M / 4 + 255) / 256;
        int cb = ((M * EMB) / 4 + 255) / 256;
        int prep_blocks = zb + cb + 8 + 32 + 32;
        prep_kernel<<<prep_blocks, 256, 0, stream>>>(
            emb, W0, W1, W2, counts, embb, W0f, W1f, W2f, M, zb, cb);

        // CSR build
        hist_kernel<<<(E / 4 + 255) / 256, 256, 0, stream>>>(row, counts, E);
        int nb = (M + 1023) / 1024;
        scan_phase1<<<nb, 256, 0, stream>>>(counts, offs, bsums, M);
        scan_phase23<<<(M + 255) / 256, 256, 0, stream>>>(offs, bsums, cursor, M, nb);
        scatter_kernel<<<(E + 255) / 256, 256, 0, stream>>>(row, col, val, cursor, edata, E);

        // pull SpMM -> xb (bf16): grid-stride, lane-group edge parallelism
        int pull_blocks = (M + 4 * ROWS_PER_WAVE - 1) / (4 * ROWS_PER_WAVE);
        pull_kernel<<<pull_blocks, 256, 0, stream>>>(offs, counts, edata, embb, xb, M);

        // fused 3-layer MLP -> out (BM=32, cross-barrier W prefetch)
        int gblocks = (M + 31) / 32;
        mlp_fused<<<gblocks, 256, 0, stream>>>(xb, W0f, W1f, W2f, out, M);
    } else {
        // fp32 fallback (ws too small): atomic scatter SpMM + fp32 GEMMs
        float* x = (float*)ws;
        (void)hipMemsetAsync(x, 0, (size_t)M * EMB * sizeof(float), stream);
        spmm_kernel<<<(E + 3) / 4, 256, 0, stream>>>(row, col, val, emb, x, E);
        int gblocks = (M + 63) / 64;
        gemm_f32<EMB, true ><<<gblocks, 256, 0, stream>>>(x,   W0, out, M);
        gemm_f32<HID, true ><<<gblocks, 256, 0, stream>>>(out, W1, out, M);
        gemm_f32<HID, false><<<gblocks, 256, 0, stream>>>(out, W2, out, M);
    }
}